// Round 1
// baseline (237.976 us; speedup 1.0000x reference)
//
#include <hip/hip_runtime.h>

namespace {

constexpr int T_STEPS = 1024;
constexpr int BATCH   = 16;
constexpr int NNEUR   = 2048;
constexpr int MCOLS   = 512;
constexpr int BN      = BATCH * NNEUR;   // 32768

// doubles first (mirror python scalar math), then cast to f32 like jax weak typing
constexpr double DT_D   = 1e-7;
constexpr double CMEM_D = 1e-12;
constexpr double GLK_D  = 1e-9;
constexpr double TAU_D  = 1e-4;

constexpr float DT_F     = (float)DT_D;              // 1e-7f
constexpr float CMEM_F   = (float)CMEM_D;            // 1e-12f
constexpr float GLEAK_F  = (float)GLK_D;             // 1e-9f
constexpr float VTH_F    = (float)(0.7 * 1.0);       // VTH * GAIN
constexpr float REFRAC_F = (float)1e-6;
constexpr float AINC_F   = (float)5e-11;
constexpr float DECAY_F  = (float)(1.0 - DT_D / TAU_D);   // 0.999f
constexpr float VRESET_F = 0.0f;

constexpr int CHUNK = 16;   // steps per register buffer

} // namespace

// One LIF step, mirroring the jax op order in f32.
#define LIF_STEP(ec, ic, vc, tidx)                                         \
    do {                                                                   \
        float t      = (float)(tidx) * DT_F;                               \
        bool  active = (t - ls) >= REFRAC_F;                               \
        float totI   = ((ec) - A) + (ic);                                  \
        float Vn     = (V + (DT_F * (totI - GLEAK_F * V)) / CMEM_F) + (vc);\
        float An     = A * DECAY_F;                                        \
        float V1     = active ? Vn : V;                                    \
        float A1     = active ? An : A;                                    \
        bool  spike  = active && (V1 >= VTH_F);                            \
        V  = spike ? VRESET_F : V1;                                        \
        A  = spike ? (A1 + AINC_F) : A1;                                   \
        ls = spike ? t : ls;                                               \
        count += spike ? 1 : 0;                                            \
    } while (0)

__global__ __launch_bounds__(64) void lif_sim_kernel(
    const float* __restrict__ ext,
    const float* __restrict__ inz,
    const float* __restrict__ vnz,
    float* __restrict__ rates)
{
    const int g = blockIdx.x * 64 + threadIdx.x;   // g = b*N + n, 0..32767

    const float* pe = ext + g;
    const float* pi = inz + g;
    const float* pv = vnz + g;

    float e0[CHUNK], i0[CHUNK], v0[CHUNK];
    float e1[CHUNK], i1[CHUNK], v1b[CHUNK];

    float V = 0.0f, A = 0.0f, ls = -1e9f;
    int count = 0;

    // prologue: chunk 0 into buffer 0
#pragma unroll
    for (int c = 0; c < CHUNK; ++c) {
        int o = c * BN;
        e0[c] = pe[o]; i0[c] = pi[o]; v0[c] = pv[o];
    }

    for (int tb = 0; tb < T_STEPS; tb += 2 * CHUNK) {
        // prefetch chunk (tb+CHUNK) into buffer 1 (always in range: tb+CHUNK <= 1008)
#pragma unroll
        for (int c = 0; c < CHUNK; ++c) {
            int o = (tb + CHUNK + c) * BN;
            e1[c] = pe[o]; i1[c] = pi[o]; v1b[c] = pv[o];
        }
        // compute buffer 0 (steps tb .. tb+CHUNK-1)
#pragma unroll
        for (int c = 0; c < CHUNK; ++c) {
            LIF_STEP(e0[c], i0[c], v0[c], tb + c);
        }
        // prefetch chunk (tb+2*CHUNK) into buffer 0, if in range
        if (tb + 2 * CHUNK < T_STEPS) {
#pragma unroll
            for (int c = 0; c < CHUNK; ++c) {
                int o = (tb + 2 * CHUNK + c) * BN;
                e0[c] = pe[o]; i0[c] = pi[o]; v0[c] = pv[o];
            }
        }
        // compute buffer 1 (steps tb+CHUNK .. tb+2*CHUNK-1)
#pragma unroll
        for (int c = 0; c < CHUNK; ++c) {
            LIF_STEP(e1[c], i1[c], v1b[c], tb + CHUNK + c);
        }
    }

    rates[g] = (float)count * (1.0f / 1024.0f);   // mean over T=1024 (exact)
}

// Partial readout GEMM: out_part[kc][b][m] = sum over k-chunk of rates[b,k]*w[k,m]
// grid: (M/64 m-tiles, KC k-chunks), block: 64 threads (one m each)
constexpr int KC = 8;
constexpr int KCHUNK = NNEUR / KC;   // 256

__global__ __launch_bounds__(64) void readout_partial_kernel(
    const float* __restrict__ rates,
    const float* __restrict__ G,
    const float* __restrict__ cn,
    float* __restrict__ part)
{
    const int m  = blockIdx.x * 64 + threadIdx.x;  // 0..511
    const int kc = blockIdx.y;                     // 0..KC-1
    const int k0 = kc * KCHUNK;

    float acc[BATCH];
#pragma unroll
    for (int b = 0; b < BATCH; ++b) acc[b] = 0.0f;

    for (int k = k0; k < k0 + KCHUNK; ++k) {
        float g = G[k * MCOLS + m];
        float c = cn[k * MCOLS + m];
        float w = fmaxf(1e-8f, g * (1.0f + 0.1118f * c)) * 0.1f;  // Gn * READ_V
#pragma unroll
        for (int b = 0; b < BATCH; ++b) {
            acc[b] = fmaf(rates[b * NNEUR + k], w, acc[b]);
        }
    }

#pragma unroll
    for (int b = 0; b < BATCH; ++b) {
        part[(kc * BATCH + b) * MCOLS + m] = acc[b];
    }
}

__global__ __launch_bounds__(256) void readout_reduce_kernel(
    const float* __restrict__ part,
    float* __restrict__ out)
{
    const int i = blockIdx.x * 256 + threadIdx.x;  // 0..8191 = b*512+m
    float s = 0.0f;
#pragma unroll
    for (int kc = 0; kc < KC; ++kc) {
        s += part[kc * (BATCH * MCOLS) + i];
    }
    out[i] = s;
}

extern "C" void kernel_launch(void* const* d_in, const int* in_sizes, int n_in,
                              void* d_out, int out_size, void* d_ws, size_t ws_size,
                              hipStream_t stream)
{
    const float* ext = (const float*)d_in[0];   // [T,B,N]
    const float* inz = (const float*)d_in[1];   // [T,B,N]
    const float* vnz = (const float*)d_in[2];   // [T,B,N]
    const float* G   = (const float*)d_in[3];   // [N,M]
    const float* cn  = (const float*)d_in[4];   // [N,M]
    float* out = (float*)d_out;                 // [B,M] = 8192

    float* rates = (float*)d_ws;                // 32768 floats
    float* part  = rates + BN;                  // KC*16*512 = 65536 floats

    lif_sim_kernel<<<BN / 64, 64, 0, stream>>>(ext, inz, vnz, rates);
    readout_partial_kernel<<<dim3(MCOLS / 64, KC), 64, 0, stream>>>(rates, G, cn, part);
    readout_reduce_kernel<<<(BATCH * MCOLS) / 256, 256, 0, stream>>>(part, out);
}

// Round 2
// 126.311 us; speedup vs baseline: 1.8840x; 1.8840x over previous
//
#include <hip/hip_runtime.h>

namespace {

constexpr int T_STEPS = 1024;
constexpr int BATCH   = 16;
constexpr int NNEUR   = 2048;
constexpr int MCOLS   = 512;
constexpr int BN      = BATCH * NNEUR;   // 32768

// doubles first (mirror python scalar math), then cast to f32 like jax weak typing
constexpr double DT_D   = 1e-7;
constexpr double CMEM_D = 1e-12;
constexpr double GLK_D  = 1e-9;
constexpr double TAU_D  = 1e-4;

constexpr float DT_F     = (float)DT_D;              // 1e-7f
constexpr float CMEM_F   = (float)CMEM_D;            // 1e-12f
constexpr float GLEAK_F  = (float)GLK_D;             // 1e-9f
constexpr float VTH_F    = (float)(0.7 * 1.0);       // VTH * GAIN
constexpr float REFRAC_F = (float)1e-6;
constexpr float AINC_F   = (float)5e-11;
constexpr float DECAY_F  = (float)(1.0 - DT_D / TAU_D);   // 0.999f
constexpr float VRESET_F = 0.0f;

constexpr int C_STEPS = 16;               // steps per LDS buffer
constexpr int NBUF    = T_STEPS / C_STEPS; // 64 buffers
constexpr int RING    = 5;                // LDS ring depth
constexpr int AHEAD   = 4;                // prefetch distance (buffers)
constexpr int LPB     = 12;               // global_load_lds instrs per buffer (3 arrays x 4)

} // namespace

// One LIF step, mirroring the jax op order in f32 (numerics identical to the
// round-1 passing kernel).
#define LIF_STEP(ec, ic, vc, tidx)                                         \
    do {                                                                   \
        float t      = (float)(tidx) * DT_F;                               \
        bool  active = (t - ls) >= REFRAC_F;                               \
        float totI   = ((ec) - A) + (ic);                                  \
        float Vn     = (V + (DT_F * (totI - GLEAK_F * V)) / CMEM_F) + (vc);\
        float An     = A * DECAY_F;                                        \
        float V1     = active ? Vn : V;                                    \
        float A1     = active ? An : A;                                    \
        bool  spike  = active && (V1 >= VTH_F);                            \
        V  = spike ? VRESET_F : V1;                                        \
        A  = spike ? (A1 + AINC_F) : A1;                                   \
        ls = spike ? t : ls;                                               \
        count += spike ? 1 : 0;                                            \
    } while (0)

// Single wave per block: producer == consumer, so ordering needs only this
// wave's own counted vmcnt — no barriers, no cross-wave races.
__global__ __launch_bounds__(64) void lif_sim_kernel(
    const float* __restrict__ ext,
    const float* __restrict__ inz,
    const float* __restrict__ vnz,
    float* __restrict__ rates)
{
    // ring buffer: [slot][array][t within buffer][neuron]  (60 KB)
    __shared__ float lds[RING][3][C_STEPS][64];

    const int lane = threadIdx.x;
    const int g0   = blockIdx.x * 64;

    // global_load_lds width-16 lane mapping: LDS dst is base + lane*16 (linear).
    // lane l supplies the global address of [t = q*4 + (l>>4)][n = (l&15)*4 .. +3]
    const int tsub = lane >> 4;         // 0..3
    const int nsub = (lane & 15) * 4;   // 0,4,...,60

    auto issue = [&](int j) {
        const int slot = j % RING;
#pragma unroll
        for (int a = 0; a < 3; ++a) {
            const float* base = (a == 0) ? ext : ((a == 1) ? inz : vnz);
#pragma unroll
            for (int q = 0; q < 4; ++q) {
                const float* gp = base +
                    (size_t)(j * C_STEPS + q * 4 + tsub) * BN + (g0 + nsub);
                __builtin_amdgcn_global_load_lds(
                    (const __attribute__((address_space(1))) void*)gp,
                    (__attribute__((address_space(3))) void*)&lds[slot][a][q * 4][0],
                    16, 0, 0);
            }
        }
    };

    float V = 0.0f, A = 0.0f, ls = -1e9f;
    int count = 0;

    // prologue: fill prefetch pipe with buffers 0..AHEAD-1
    for (int j = 0; j < AHEAD; ++j) issue(j);

    for (int k = 0; k < NBUF; ++k) {
        if (k + AHEAD < NBUF) issue(k + AHEAD);

        // outstanding after issue = LPB * min(AHEAD, NBUF-1-k); waiting down to
        // that count guarantees buffer k's 12 loads have landed in LDS.
        const int rem = NBUF - 1 - k;
        const int nb  = (rem < AHEAD) ? rem : AHEAD;
        switch (nb) {
            case 4: asm volatile("s_waitcnt vmcnt(48)" ::: "memory"); break;
            case 3: asm volatile("s_waitcnt vmcnt(36)" ::: "memory"); break;
            case 2: asm volatile("s_waitcnt vmcnt(24)" ::: "memory"); break;
            case 1: asm volatile("s_waitcnt vmcnt(12)" ::: "memory"); break;
            default: asm volatile("s_waitcnt vmcnt(0)" ::: "memory"); break;
        }
        __builtin_amdgcn_sched_barrier(0);

        const int slot = k % RING;
#pragma unroll
        for (int c = 0; c < C_STEPS; ++c) {
            float ec = lds[slot][0][c][lane];
            float ic = lds[slot][1][c][lane];
            float vc = lds[slot][2][c][lane];
            LIF_STEP(ec, ic, vc, k * C_STEPS + c);
        }
    }

    rates[g0 + lane] = (float)count * (1.0f / 1024.0f);   // mean over T=1024 (exact)
}

// ---------------- readout: rates[16,2048] @ (Gn*0.1)[2048,512] ----------------
// Stage 1: grid (8 m-tiles, KC k-chunks), 256 threads = 64 m-cols x 4 k-subs;
// intra-block LDS reduce over the 4 subs -> part[kc][b][m].
constexpr int KC   = 8;
constexpr int KCH  = NNEUR / KC;    // 256 k per chunk
constexpr int KSUB = 4;             // waves per block splitting the chunk
constexpr int KPT  = KCH / KSUB;    // 64 k per thread

__global__ __launch_bounds__(256) void readout_partial_kernel(
    const float* __restrict__ rates,
    const float* __restrict__ G,
    const float* __restrict__ cn,
    float* __restrict__ part)
{
    __shared__ float red[KSUB][64][BATCH + 1];   // +1 pad vs bank conflicts

    const int tid = threadIdx.x;
    const int ml  = tid & 63;
    const int s   = tid >> 6;
    const int m   = blockIdx.x * 64 + ml;
    const int kc  = blockIdx.y;
    const int k0  = kc * KCH + s * KPT;

    float acc[BATCH];
#pragma unroll
    for (int b = 0; b < BATCH; ++b) acc[b] = 0.0f;

#pragma unroll 4
    for (int k = k0; k < k0 + KPT; ++k) {
        float g = G[(size_t)k * MCOLS + m];
        float c = cn[(size_t)k * MCOLS + m];
        float w = fmaxf(1e-8f, g * (1.0f + 0.1118f * c)) * 0.1f;  // Gn * READ_V
#pragma unroll
        for (int b = 0; b < BATCH; ++b) {
            acc[b] = fmaf(rates[b * NNEUR + k], w, acc[b]);
        }
    }

#pragma unroll
    for (int b = 0; b < BATCH; ++b) red[s][ml][b] = acc[b];
    __syncthreads();

    if (s == 0) {
#pragma unroll
        for (int b = 0; b < BATCH; ++b) {
            float v = ((red[0][ml][b] + red[1][ml][b]) + red[2][ml][b]) + red[3][ml][b];
            part[((size_t)kc * BATCH + b) * MCOLS + m] = v;
        }
    }
}

__global__ __launch_bounds__(256) void readout_reduce_kernel(
    const float* __restrict__ part,
    float* __restrict__ out)
{
    const int i = blockIdx.x * 256 + threadIdx.x;  // 0..8191 = b*512+m
    float s = 0.0f;
#pragma unroll
    for (int kc = 0; kc < KC; ++kc) {
        s += part[kc * (BATCH * MCOLS) + i];
    }
    out[i] = s;
}

extern "C" void kernel_launch(void* const* d_in, const int* in_sizes, int n_in,
                              void* d_out, int out_size, void* d_ws, size_t ws_size,
                              hipStream_t stream)
{
    const float* ext = (const float*)d_in[0];   // [T,B,N]
    const float* inz = (const float*)d_in[1];   // [T,B,N]
    const float* vnz = (const float*)d_in[2];   // [T,B,N]
    const float* G   = (const float*)d_in[3];   // [N,M]
    const float* cn  = (const float*)d_in[4];   // [N,M]
    float* out = (float*)d_out;                 // [B,M] = 8192

    float* rates = (float*)d_ws;                // 32768 floats
    float* part  = rates + BN;                  // 8*16*512 = 65536 floats (same 384KB ws footprint as round 1)

    lif_sim_kernel<<<BN / 64, 64, 0, stream>>>(ext, inz, vnz, rates);
    readout_partial_kernel<<<dim3(MCOLS / 64, KC), 256, 0, stream>>>(rates, G, cn, part);
    readout_reduce_kernel<<<(BATCH * MCOLS) / 256, 256, 0, stream>>>(part, out);
}